// Round 3
// baseline (329.616 us; speedup 1.0000x reference)
//
#include <hip/hip_runtime.h>

#define NC 32
#define NR 512

typedef float nf4 __attribute__((ext_vector_type(4)));  // native vec for NT store

// ---------------------------------------------------------------------------
// Kernel 1: transpose the three [C=32, R=512] tables into [R=512, C=32] in ws
// so all 32 components of one resolution row are one contiguous 128 B line.
// ---------------------------------------------------------------------------
__global__ __launch_bounds__(256) void transpose_vecs(
    const float* __restrict__ vx, const float* __restrict__ vy,
    const float* __restrict__ vz, float* __restrict__ tx,
    float* __restrict__ ty, float* __restrict__ tz) {
  int u = blockIdx.x * 256 + threadIdx.x;           // 0 .. 3*16384-1
  if (u >= 3 * NC * NR) return;
  int table = u >> 14;                              // /16384
  int e = u & (NC * NR - 1);                        // c*512 + r
  int c = e >> 9;
  int r = e & (NR - 1);
  const float* src = (table == 0) ? vx : (table == 1) ? vy : vz;
  float* dst = (table == 0) ? tx : (table == 1) ? ty : tz;
  dst[r * NC + c] = src[e];
}

// Precomputed per-(point,axis) sample: row offsets (in floats) + masked weights.
// grid_sample(align_corners=True, padding='zeros'): validity folded into weight.
struct Samp {
  int o0, o1;
  float m0, m1;
};

__device__ __forceinline__ Samp prep(float x) {
  float ix = (x + 1.0f) * 0.5f * (float)(NR - 1);
  float f = floorf(ix);
  float w = ix - f;
  int i0 = (int)f;
  int i1 = i0 + 1;
  Samp s;
  s.m0 = (i0 >= 0 && i0 < NR) ? (1.0f - w) : 0.0f;
  s.m1 = (i1 >= 0 && i1 < NR) ? w : 0.0f;
  s.o0 = min(max(i0, 0), NR - 1) * NC;
  s.o1 = min(max(i1, 0), NR - 1) * NC;
  return s;
}

__device__ __forceinline__ float4 lerp4(float4 a, float4 b, float m0, float m1) {
  float4 r;
  r.x = a.x * m0 + b.x * m1;
  r.y = a.y * m0 + b.y * m1;
  r.z = a.z * m0 + b.z * m1;
  r.w = a.w * m0 + b.w * m1;
  return r;
}

// ---------------------------------------------------------------------------
// Kernel 2: one thread = 4 components x 4 points. 8 lanes share a point-group.
// All 24 table loads are issued back-to-back before any use -> ~24 KB of
// memory requests in flight per wave (vs 6 KB before) to hide L2 latency.
// ---------------------------------------------------------------------------
__global__ __launch_bounds__(256) void cp_encode4(
    const float* __restrict__ pos, const float* __restrict__ tx,
    const float* __restrict__ ty, const float* __restrict__ tz,
    float* __restrict__ out, int npts) {
  int t = blockIdx.x * 256 + threadIdx.x;
  int pg = t >> 3;             // point-group (4 points)
  int c4 = (t & 7) * 4;        // first component of this thread's quad
  int p0 = pg * 4;
  if (p0 >= npts) return;

  float px[4], py[4], pz[4];
  if (p0 + 4 <= npts) {
    // 12 contiguous floats -> 3 float4 loads (broadcast across the 8 lanes
    // sharing this point-group; 384 B contiguous per wave).
    const float4* pv = (const float4*)(pos + (size_t)p0 * 3);
    float4 a = pv[0], b = pv[1], c = pv[2];
    px[0] = a.x; py[0] = a.y; pz[0] = a.z;
    px[1] = a.w; py[1] = b.x; pz[1] = b.y;
    px[2] = b.z; py[2] = b.w; pz[2] = c.x;
    px[3] = c.y; py[3] = c.z; pz[3] = c.w;
  } else {
#pragma unroll
    for (int j = 0; j < 4; ++j) {
      int p = min(p0 + j, npts - 1);
      px[j] = pos[3 * p + 0];
      py[j] = pos[3 * p + 1];
      pz[j] = pos[3 * p + 2];
    }
  }

  Samp sx[4], sy[4], sz[4];
#pragma unroll
  for (int j = 0; j < 4; ++j) {
    sx[j] = prep(px[j]);
    sy[j] = prep(py[j]);
    sz[j] = prep(pz[j]);
  }

  // Issue all 24 gathers before any consume (max memory-level parallelism).
  float4 vx0[4], vx1[4], vy0[4], vy1[4], vz0[4], vz1[4];
#pragma unroll
  for (int j = 0; j < 4; ++j) {
    vx0[j] = *(const float4*)(tx + sx[j].o0 + c4);
    vx1[j] = *(const float4*)(tx + sx[j].o1 + c4);
    vy0[j] = *(const float4*)(ty + sy[j].o0 + c4);
    vy1[j] = *(const float4*)(ty + sy[j].o1 + c4);
    vz0[j] = *(const float4*)(tz + sz[j].o0 + c4);
    vz1[j] = *(const float4*)(tz + sz[j].o1 + c4);
  }

#pragma unroll
  for (int j = 0; j < 4; ++j) {
    int p = p0 + j;
    if (p < npts) {
      float4 fx = lerp4(vx0[j], vx1[j], sx[j].m0, sx[j].m1);
      float4 fy = lerp4(vy0[j], vy1[j], sy[j].m0, sy[j].m1);
      float4 fz = lerp4(vz0[j], vz1[j], sz[j].m0, sz[j].m1);
      nf4 r;
      r.x = fx.x * fy.x * fz.x;
      r.y = fx.y * fy.y * fz.y;
      r.z = fx.z * fy.z * fz.z;
      r.w = fx.w * fy.w * fz.w;
      // Non-temporal: out is write-once, keep it out of L2 (tables live there).
      __builtin_nontemporal_store(r, (nf4*)(out + (size_t)p * NC + c4));
    }
  }
}

extern "C" void kernel_launch(void* const* d_in, const int* in_sizes, int n_in,
                              void* d_out, int out_size, void* d_ws,
                              size_t ws_size, hipStream_t stream) {
  const float* pos = (const float*)d_in[0];
  const float* vx = (const float*)d_in[1];
  const float* vy = (const float*)d_in[2];
  const float* vz = (const float*)d_in[3];
  float* out = (float*)d_out;
  int npts = in_sizes[0] / 3;

  float* tx = (float*)d_ws;
  float* ty = tx + NC * NR;
  float* tz = ty + NC * NR;
  int tb = (3 * NC * NR + 255) / 256;
  transpose_vecs<<<tb, 256, 0, stream>>>(vx, vy, vz, tx, ty, tz);

  int pgroups = (npts + 3) / 4;
  int total_threads = pgroups * 8;        // 8 lanes (comp-quads) per group
  int blocks = (total_threads + 255) / 256;
  cp_encode4<<<blocks, 256, 0, stream>>>(pos, tx, ty, tz, out, npts);
}